// Round 1
// baseline (420.499 us; speedup 1.0000x reference)
//
#include <hip/hip_runtime.h>
#include <hip/hip_bf16.h>

typedef __attribute__((ext_vector_type(8))) short bf16x8;
typedef __attribute__((ext_vector_type(4))) float f32x4;

constexpr int Bc = 2, Sc = 2048, Ec = 1024, Hc = 16, DKc = 64;

__device__ __forceinline__ unsigned short f2b(float f) {
    union { float f; unsigned u; } v; v.f = f;
    unsigned u = v.u;
    return (unsigned short)((u + 0x7FFFu + ((u >> 16) & 1u)) >> 16);
}

// ---------------- Kernel A: QKV projection ----------------
// Y = X * W + b  (M=4096, N=1024, K=1024), bf16 MFMA, fp32 accum.
// z=0: Q scaled by 1/8 -> [B,H,S,DK]; z=1: K -> [B,H,S,DK]; z=2: V -> [B,H,DK,S] (transposed)
__global__ __launch_bounds__(256) void qkv_proj(
    const float* __restrict__ Xq, const float* __restrict__ Xk, const float* __restrict__ Xv,
    const float* __restrict__ Wq, const float* __restrict__ bq,
    const float* __restrict__ Wk, const float* __restrict__ bk,
    const float* __restrict__ Wv, const float* __restrict__ bv,
    unsigned short* __restrict__ Qw, unsigned short* __restrict__ Kw,
    unsigned short* __restrict__ Vt)
{
    const int z = blockIdx.z;
    const float* X    = (z == 0) ? Xq : (z == 1) ? Xk : Xv;
    const float* W    = (z == 0) ? Wq : (z == 1) ? Wk : Wv;
    const float* bias = (z == 0) ? bq : (z == 1) ? bk : bv;

    __shared__ unsigned short As[128][40];  // [m][k], padded
    __shared__ unsigned short Bs[128][40];  // [n][k], padded (W transposed)

    const int tid = threadIdx.x;
    const int m0 = blockIdx.y * 128, n0 = blockIdx.x * 128;
    const int lane = tid & 63, c = lane & 15, g = lane >> 4;
    const int w = tid >> 6;
    const int wr = (w >> 1) * 64, wc = (w & 1) * 64;

    f32x4 acc[4][4] = {};

    for (int k0 = 0; k0 < Ec; k0 += 32) {
        // stage A tile 128x32 (fp32 -> bf16)
        {
            const int r = tid >> 3, c4 = (tid & 7) * 4;
            #pragma unroll
            for (int p = 0; p < 4; p++) {
                float4 v = *(const float4*)&X[(size_t)(m0 + r + 32 * p) * Ec + k0 + c4];
                ushort4 h; h.x = f2b(v.x); h.y = f2b(v.y); h.z = f2b(v.z); h.w = f2b(v.w);
                *(ushort4*)&As[r + 32 * p][c4] = h;
            }
        }
        // stage B tile: W[k][n] -> Bs[n][k] (transpose, fp32 -> bf16)
        {
            const int kk = tid >> 5, cn = (tid & 31) * 4;
            #pragma unroll
            for (int p = 0; p < 4; p++) {
                float4 v = *(const float4*)&W[(size_t)(k0 + kk + 8 * p) * Ec + n0 + cn];
                Bs[cn + 0][kk + 8 * p] = f2b(v.x);
                Bs[cn + 1][kk + 8 * p] = f2b(v.y);
                Bs[cn + 2][kk + 8 * p] = f2b(v.z);
                Bs[cn + 3][kk + 8 * p] = f2b(v.w);
            }
        }
        __syncthreads();
        bf16x8 a[4], b[4];
        #pragma unroll
        for (int m = 0; m < 4; m++) a[m] = *(const bf16x8*)&As[wr + m * 16 + c][8 * g];
        #pragma unroll
        for (int n = 0; n < 4; n++) b[n] = *(const bf16x8*)&Bs[wc + n * 16 + c][8 * g];
        #pragma unroll
        for (int m = 0; m < 4; m++)
            #pragma unroll
            for (int n = 0; n < 4; n++)
                acc[m][n] = __builtin_amdgcn_mfma_f32_16x16x32_bf16(a[m], b[n], acc[m][n], 0, 0, 0);
        __syncthreads();
    }

    // epilogue: bias + scatter to head layout
    #pragma unroll
    for (int n = 0; n < 4; n++) {
        const int gn = n0 + wc + n * 16 + c;       // e index
        const float bv_ = bias[gn];
        const int h = gn >> 6, d = gn & 63;
        #pragma unroll
        for (int m = 0; m < 4; m++) {
            #pragma unroll
            for (int r = 0; r < 4; r++) {
                const int gm = m0 + wr + m * 16 + 4 * g + r;  // b*S+s
                const int bb = gm >> 11, s = gm & 2047;
                const float val = acc[m][n][r] + bv_;
                if (z == 0)
                    Qw[((size_t)(bb * Hc + h) * Sc + s) * DKc + d] = f2b(val * 0.125f);
                else if (z == 1)
                    Kw[((size_t)(bb * Hc + h) * Sc + s) * DKc + d] = f2b(val);
                else
                    Vt[((size_t)(bb * Hc + h) * DKc + d) * Sc + s] = f2b(val);
            }
        }
    }
}

// ---------------- Kernel B: causal flash attention ----------------
// grid (S/64, B*H); 4 waves/block, each wave owns 16 q rows.
__global__ __launch_bounds__(256) void attn(
    const unsigned short* __restrict__ Qw, const unsigned short* __restrict__ Kw,
    const unsigned short* __restrict__ Vt, unsigned short* __restrict__ Ctx)
{
    const int bh = blockIdx.y;
    const int qbase = blockIdx.x * 64;
    const int tid = threadIdx.x, w = tid >> 6, lane = tid & 63;
    const int c = lane & 15, g = lane >> 4;
    const int bb = bh >> 4, hh = bh & 15;

    const unsigned short* Qh = Qw + (size_t)bh * Sc * DKc;
    const unsigned short* Kh = Kw + (size_t)bh * Sc * DKc;
    const unsigned short* Vh = Vt + (size_t)bh * DKc * Sc;

    __shared__ unsigned short Pl[4][16][40];  // per-wave P bounce, padded

    const int qrow = qbase + w * 16 + c;  // q row this lane's softmax state tracks
    const bf16x8 q0 = *(const bf16x8*)&Qh[(size_t)qrow * DKc + 8 * g];
    const bf16x8 q1 = *(const bf16x8*)&Qh[(size_t)qrow * DKc + 32 + 8 * g];

    float mrun = -1e30f, lrun = 0.f;
    f32x4 o[4] = {};  // dk chunks; row = 4g+r (local q), col = c (dk in chunk)

    const int ntiles = (qbase + 64) >> 5;
    for (int j = 0; j < ntiles; j++) {
        const int kv0 = j * 32;
        // swapped QK^T: D_t[kv][q] = K_tile * Q^T
        f32x4 d0 = {}, d1 = {};
        {
            bf16x8 k00 = *(const bf16x8*)&Kh[(size_t)(kv0 + c) * DKc + 8 * g];
            bf16x8 k01 = *(const bf16x8*)&Kh[(size_t)(kv0 + c) * DKc + 32 + 8 * g];
            bf16x8 k10 = *(const bf16x8*)&Kh[(size_t)(kv0 + 16 + c) * DKc + 8 * g];
            bf16x8 k11 = *(const bf16x8*)&Kh[(size_t)(kv0 + 16 + c) * DKc + 32 + 8 * g];
            d0 = __builtin_amdgcn_mfma_f32_16x16x32_bf16(k00, q0, d0, 0, 0, 0);
            d0 = __builtin_amdgcn_mfma_f32_16x16x32_bf16(k01, q1, d0, 0, 0, 0);
            d1 = __builtin_amdgcn_mfma_f32_16x16x32_bf16(k10, q0, d1, 0, 0, 0);
            d1 = __builtin_amdgcn_mfma_f32_16x16x32_bf16(k11, q1, d1, 0, 0, 0);
        }
        // causal mask + online softmax (state per lane for q=c, replicated over g)
        float s0[4], s1[4];
        float tmax = -1e30f;
        #pragma unroll
        for (int r = 0; r < 4; r++) {
            const int kva = kv0 + 4 * g + r;
            const int kvb = kv0 + 16 + 4 * g + r;
            s0[r] = (kva <= qrow) ? d0[r] : -1e30f;
            s1[r] = (kvb <= qrow) ? d1[r] : -1e30f;
            tmax = fmaxf(tmax, fmaxf(s0[r], s1[r]));
        }
        tmax = fmaxf(tmax, __shfl_xor(tmax, 16));
        tmax = fmaxf(tmax, __shfl_xor(tmax, 32));
        const float mnew = fmaxf(mrun, tmax);
        const float alpha = __expf(mrun - mnew);
        float tsum = 0.f;
        #pragma unroll
        for (int r = 0; r < 4; r++) {
            s0[r] = __expf(s0[r] - mnew);
            s1[r] = __expf(s1[r] - mnew);
            tsum += s0[r] + s1[r];
        }
        tsum += __shfl_xor(tsum, 16);
        tsum += __shfl_xor(tsum, 32);
        lrun = lrun * alpha + tsum;
        mrun = mnew;

        // P -> bf16, bounce through LDS to reach A-operand layout
        ushort4 p0, p1;
        p0.x = f2b(s0[0]); p0.y = f2b(s0[1]); p0.z = f2b(s0[2]); p0.w = f2b(s0[3]);
        p1.x = f2b(s1[0]); p1.y = f2b(s1[1]); p1.z = f2b(s1[2]); p1.w = f2b(s1[3]);
        *(ushort4*)&Pl[w][c][4 * g]      = p0;   // kv-local 4g..4g+3
        *(ushort4*)&Pl[w][c][16 + 4 * g] = p1;   // kv-local 16+4g..
        __syncthreads();
        const bf16x8 pA = *(const bf16x8*)&Pl[w][c][8 * g];  // row=c(q), k=kv 8g..8g+7

        // rescale factors for rows 4g+r
        float alpha_r[4];
        #pragma unroll
        for (int r = 0; r < 4; r++) alpha_r[r] = __shfl(alpha, 4 * g + r);

        // PV: o[ch] = P(16x32) * V(32x16) + alpha*o
        #pragma unroll
        for (int ch = 0; ch < 4; ch++) {
            const bf16x8 vB = *(const bf16x8*)&Vh[(size_t)(ch * 16 + c) * Sc + kv0 + 8 * g];
            f32x4 t = o[ch];
            #pragma unroll
            for (int r = 0; r < 4; r++) t[r] *= alpha_r[r];
            o[ch] = __builtin_amdgcn_mfma_f32_16x16x32_bf16(pA, vB, t, 0, 0, 0);
        }
        __syncthreads();
    }

    // normalize + store ctx as bf16 [B,S,E]
    float linv[4];
    #pragma unroll
    for (int r = 0; r < 4; r++) {
        const float l = __shfl(lrun, 4 * g + r);
        linv[r] = 1.f / l;
    }
    #pragma unroll
    for (int ch = 0; ch < 4; ch++) {
        #pragma unroll
        for (int r = 0; r < 4; r++) {
            const int qg = qbase + w * 16 + 4 * g + r;
            const int e = hh * 64 + ch * 16 + c;
            Ctx[((size_t)(bb * Sc + qg)) * Ec + e] = f2b(o[ch][r] * linv[r]);
        }
    }
}

// ---------------- Kernel C: output projection ----------------
__global__ __launch_bounds__(256) void out_proj(
    const unsigned short* __restrict__ Ctx, const float* __restrict__ Wo,
    const float* __restrict__ bo, float* __restrict__ Out)
{
    __shared__ unsigned short As[128][40];
    __shared__ unsigned short Bs[128][40];

    const int tid = threadIdx.x;
    const int m0 = blockIdx.y * 128, n0 = blockIdx.x * 128;
    const int lane = tid & 63, c = lane & 15, g = lane >> 4;
    const int w = tid >> 6;
    const int wr = (w >> 1) * 64, wc = (w & 1) * 64;

    f32x4 acc[4][4] = {};

    for (int k0 = 0; k0 < Ec; k0 += 32) {
        {   // A tile: bf16 direct
            const int r = tid >> 2, c8 = (tid & 3) * 8;
            #pragma unroll
            for (int p = 0; p < 2; p++) {
                ushort4 v0 = *(const ushort4*)&Ctx[(size_t)(m0 + r + 64 * p) * Ec + k0 + c8];
                ushort4 v1 = *(const ushort4*)&Ctx[(size_t)(m0 + r + 64 * p) * Ec + k0 + c8 + 4];
                *(ushort4*)&As[r + 64 * p][c8]     = v0;
                *(ushort4*)&As[r + 64 * p][c8 + 4] = v1;
            }
        }
        {   // B tile: Wo[k][n] -> Bs[n][k]
            const int kk = tid >> 5, cn = (tid & 31) * 4;
            #pragma unroll
            for (int p = 0; p < 4; p++) {
                float4 v = *(const float4*)&Wo[(size_t)(k0 + kk + 8 * p) * Ec + n0 + cn];
                Bs[cn + 0][kk + 8 * p] = f2b(v.x);
                Bs[cn + 1][kk + 8 * p] = f2b(v.y);
                Bs[cn + 2][kk + 8 * p] = f2b(v.z);
                Bs[cn + 3][kk + 8 * p] = f2b(v.w);
            }
        }
        __syncthreads();
        bf16x8 a[4], b[4];
        #pragma unroll
        for (int m = 0; m < 4; m++) a[m] = *(const bf16x8*)&As[wr + m * 16 + c][8 * g];
        #pragma unroll
        for (int n = 0; n < 4; n++) b[n] = *(const bf16x8*)&Bs[wc + n * 16 + c][8 * g];
        #pragma unroll
        for (int m = 0; m < 4; m++)
            #pragma unroll
            for (int n = 0; n < 4; n++)
                acc[m][n] = __builtin_amdgcn_mfma_f32_16x16x32_bf16(a[m], b[n], acc[m][n], 0, 0, 0);
        __syncthreads();
    }

    #pragma unroll
    for (int n = 0; n < 4; n++) {
        const int gn = n0 + wc + n * 16 + c;
        const float bv_ = bo[gn];
        #pragma unroll
        for (int m = 0; m < 4; m++) {
            #pragma unroll
            for (int r = 0; r < 4; r++) {
                const int gm = m0 + wr + m * 16 + 4 * g + r;
                Out[(size_t)gm * Ec + gn] = acc[m][n][r] + bv_;
            }
        }
    }
}

extern "C" void kernel_launch(void* const* d_in, const int* in_sizes, int n_in,
                              void* d_out, int out_size, void* d_ws, size_t ws_size,
                              hipStream_t stream) {
    const float* query = (const float*)d_in[0];
    const float* key   = (const float*)d_in[1];
    const float* value = (const float*)d_in[2];
    // d_in[3] = attn_mask (causal, implemented directly)
    const float* Wq = (const float*)d_in[4];
    const float* bq = (const float*)d_in[5];
    const float* Wk = (const float*)d_in[6];
    const float* bk = (const float*)d_in[7];
    const float* Wv = (const float*)d_in[8];
    const float* bv = (const float*)d_in[9];
    const float* Wo = (const float*)d_in[10];
    const float* bo = (const float*)d_in[11];

    const size_t n_elem = (size_t)Bc * Hc * Sc * DKc;  // 4194304
    unsigned short* Qw  = (unsigned short*)d_ws;
    unsigned short* Kw  = Qw + n_elem;
    unsigned short* Vt  = Kw + n_elem;
    unsigned short* Cx  = Vt + n_elem;

    qkv_proj<<<dim3(8, 32, 3), 256, 0, stream>>>(query, key, value, Wq, bq, Wk, bk, Wv, bv,
                                                 Qw, Kw, Vt);
    attn<<<dim3(32, 32), 256, 0, stream>>>(Qw, Kw, Vt, Cx);
    out_proj<<<dim3(8, 32), 256, 0, stream>>>(Cx, Wo, bo, (float*)d_out);
}

// Round 2
// 314.432 us; speedup vs baseline: 1.3373x; 1.3373x over previous
//
#include <hip/hip_runtime.h>
#include <hip/hip_bf16.h>

typedef __attribute__((ext_vector_type(8))) short bf16x8;
typedef __attribute__((ext_vector_type(4))) float f32x4;

constexpr int Bc = 2, Sc = 2048, Ec = 1024, Hc = 16, DKc = 64;

__device__ __forceinline__ unsigned short f2b(float f) {
    union { float f; unsigned u; } v; v.f = f;
    unsigned u = v.u;
    return (unsigned short)((u + 0x7FFFu + ((u >> 16) & 1u)) >> 16);
}

// ---------------- Kernel A: QKV projection ----------------
// Y = X * W + b  (M=4096, N=1024, K=1024), bf16 MFMA, fp32 accum.
// z=0: Q scaled by 1/8 -> [B,H,S,DK]; z=1: K -> [B,H,S,DK]; z=2: V -> [B,H,DK,S] (transposed)
__global__ __launch_bounds__(256) void qkv_proj(
    const float* __restrict__ Xq, const float* __restrict__ Xk, const float* __restrict__ Xv,
    const float* __restrict__ Wq, const float* __restrict__ bq,
    const float* __restrict__ Wk, const float* __restrict__ bk,
    const float* __restrict__ Wv, const float* __restrict__ bv,
    unsigned short* __restrict__ Qw, unsigned short* __restrict__ Kw,
    unsigned short* __restrict__ Vt)
{
    const int z = blockIdx.z;
    const float* X    = (z == 0) ? Xq : (z == 1) ? Xk : Xv;
    const float* W    = (z == 0) ? Wq : (z == 1) ? Wk : Wv;
    const float* bias = (z == 0) ? bq : (z == 1) ? bk : bv;

    __shared__ unsigned short As[128][40];  // [m][k], padded
    __shared__ unsigned short Bs[128][40];  // [n][k], padded (W transposed)

    const int tid = threadIdx.x;
    const int m0 = blockIdx.y * 128, n0 = blockIdx.x * 128;
    const int lane = tid & 63, c = lane & 15, g = lane >> 4;
    const int w = tid >> 6;
    const int wr = (w >> 1) * 64, wc = (w & 1) * 64;

    f32x4 acc[4][4] = {};

    for (int k0 = 0; k0 < Ec; k0 += 32) {
        // stage A tile 128x32 (fp32 -> bf16)
        {
            const int r = tid >> 3, c4 = (tid & 7) * 4;
            #pragma unroll
            for (int p = 0; p < 4; p++) {
                float4 v = *(const float4*)&X[(size_t)(m0 + r + 32 * p) * Ec + k0 + c4];
                ushort4 h; h.x = f2b(v.x); h.y = f2b(v.y); h.z = f2b(v.z); h.w = f2b(v.w);
                *(ushort4*)&As[r + 32 * p][c4] = h;
            }
        }
        // stage B tile: W[k][n] -> Bs[n][k] (transpose, fp32 -> bf16)
        {
            const int kk = tid >> 5, cn = (tid & 31) * 4;
            #pragma unroll
            for (int p = 0; p < 4; p++) {
                float4 v = *(const float4*)&W[(size_t)(k0 + kk + 8 * p) * Ec + n0 + cn];
                Bs[cn + 0][kk + 8 * p] = f2b(v.x);
                Bs[cn + 1][kk + 8 * p] = f2b(v.y);
                Bs[cn + 2][kk + 8 * p] = f2b(v.z);
                Bs[cn + 3][kk + 8 * p] = f2b(v.w);
            }
        }
        __syncthreads();
        bf16x8 a[4], b[4];
        #pragma unroll
        for (int m = 0; m < 4; m++) a[m] = *(const bf16x8*)&As[wr + m * 16 + c][8 * g];
        #pragma unroll
        for (int n = 0; n < 4; n++) b[n] = *(const bf16x8*)&Bs[wc + n * 16 + c][8 * g];
        #pragma unroll
        for (int m = 0; m < 4; m++)
            #pragma unroll
            for (int n = 0; n < 4; n++)
                acc[m][n] = __builtin_amdgcn_mfma_f32_16x16x32_bf16(a[m], b[n], acc[m][n], 0, 0, 0);
        __syncthreads();
    }

    // epilogue: bias + scatter to head layout
    #pragma unroll
    for (int n = 0; n < 4; n++) {
        const int gn = n0 + wc + n * 16 + c;       // e index
        const float bv_ = bias[gn];
        const int h = gn >> 6, d = gn & 63;
        #pragma unroll
        for (int m = 0; m < 4; m++) {
            #pragma unroll
            for (int r = 0; r < 4; r++) {
                const int gm = m0 + wr + m * 16 + 4 * g + r;  // b*S+s
                const int bb = gm >> 11, s = gm & 2047;
                const float val = acc[m][n][r] + bv_;
                if (z == 0)
                    Qw[((size_t)(bb * Hc + h) * Sc + s) * DKc + d] = f2b(val * 0.125f);
                else if (z == 1)
                    Kw[((size_t)(bb * Hc + h) * Sc + s) * DKc + d] = f2b(val);
                else
                    Vt[((size_t)(bb * Hc + h) * DKc + d) * Sc + s] = f2b(val);
            }
        }
    }
}

// ---------------- Kernel B: causal flash attention (v2) ----------------
// grid = 512 linear blocks: bh = id&31 (XCD locality: all pair-blocks of a
// head land on one XCD), pair = id>>5 in [0,16). Block processes q-tiles
// {pair, 31-pair} (64 rows each) => every block does exactly 33 kv64-tiles.
// 4 waves/block, each wave owns 16 q rows. No block barriers (per-wave LDS).
__global__ __launch_bounds__(256) void attn(
    const unsigned short* __restrict__ Qw, const unsigned short* __restrict__ Kw,
    const unsigned short* __restrict__ Vt, unsigned short* __restrict__ Ctx)
{
    const int L = blockIdx.x;
    const int bh = L & 31, pair = L >> 5;
    const int tid = threadIdx.x, w = tid >> 6, lane = tid & 63;
    const int c = lane & 15, g = lane >> 4;
    const int bb = bh >> 4, hh = bh & 15;

    const unsigned short* Qh = Qw + (size_t)bh * Sc * DKc;
    const unsigned short* Kh = Kw + (size_t)bh * Sc * DKc;
    const unsigned short* Vh = Vt + (size_t)bh * DKc * Sc;

    __shared__ unsigned short Pl[4][16][68];  // per-wave P bounce (pad 68: write ~2-way, read 4-way)

    for (int half = 0; half < 2; half++) {
        const int qt = half ? (31 - pair) : pair;
        const int qbase = qt * 64;
        const int qrow = qbase + w * 16 + c;

        const bf16x8 q0 = *(const bf16x8*)&Qh[(size_t)qrow * DKc + 8 * g];
        const bf16x8 q1 = *(const bf16x8*)&Qh[(size_t)qrow * DKc + 32 + 8 * g];

        float mrun = -1e30f, lrun = 0.f;
        f32x4 o[4] = {};  // row = 4g+r (local q), col = c (dk in chunk)

        const int ntiles = qt + 1;
        for (int j = 0; j < ntiles; j++) {
            const int kv0 = j * 64;
            const bool maskt = (j == qt);  // only the diagonal tile needs masking

            // issue all K and V fragment loads up front (MLP)
            bf16x8 kf[8], vf[8];
            #pragma unroll
            for (int t = 0; t < 4; t++) {
                kf[2 * t]     = *(const bf16x8*)&Kh[(size_t)(kv0 + 16 * t + c) * DKc + 8 * g];
                kf[2 * t + 1] = *(const bf16x8*)&Kh[(size_t)(kv0 + 16 * t + c) * DKc + 32 + 8 * g];
            }
            #pragma unroll
            for (int ch = 0; ch < 4; ch++) {
                vf[2 * ch]     = *(const bf16x8*)&Vh[(size_t)(ch * 16 + c) * Sc + kv0 + 8 * g];
                vf[2 * ch + 1] = *(const bf16x8*)&Vh[(size_t)(ch * 16 + c) * Sc + kv0 + 32 + 8 * g];
            }

            // swapped QK^T: D[kv_local][q_local]
            f32x4 d[4] = {};
            __builtin_amdgcn_s_setprio(1);
            #pragma unroll
            for (int t = 0; t < 4; t++) {
                d[t] = __builtin_amdgcn_mfma_f32_16x16x32_bf16(kf[2 * t], q0, d[t], 0, 0, 0);
                d[t] = __builtin_amdgcn_mfma_f32_16x16x32_bf16(kf[2 * t + 1], q1, d[t], 0, 0, 0);
            }
            __builtin_amdgcn_s_setprio(0);

            // causal mask + online softmax (state per q=c, replicated over g)
            float s[16];
            float tmax = -1e30f;
            if (maskt) {
                #pragma unroll
                for (int t = 0; t < 4; t++)
                    #pragma unroll
                    for (int r = 0; r < 4; r++) {
                        const int kv = kv0 + 16 * t + 4 * g + r;
                        const float v = (kv <= qrow) ? d[t][r] : -1e30f;
                        s[4 * t + r] = v;
                        tmax = fmaxf(tmax, v);
                    }
            } else {
                #pragma unroll
                for (int t = 0; t < 4; t++)
                    #pragma unroll
                    for (int r = 0; r < 4; r++) {
                        const float v = d[t][r];
                        s[4 * t + r] = v;
                        tmax = fmaxf(tmax, v);
                    }
            }
            tmax = fmaxf(tmax, __shfl_xor(tmax, 16));
            tmax = fmaxf(tmax, __shfl_xor(tmax, 32));
            const float mnew = fmaxf(mrun, tmax);
            const float alpha = __expf(mrun - mnew);
            float tsum = 0.f;
            #pragma unroll
            for (int i = 0; i < 16; i++) {
                s[i] = __expf(s[i] - mnew);
                tsum += s[i];
            }
            tsum += __shfl_xor(tsum, 16);
            tsum += __shfl_xor(tsum, 32);
            lrun = lrun * alpha + tsum;
            mrun = mnew;

            // P -> bf16, bounce through per-wave LDS (no block barrier needed)
            #pragma unroll
            for (int t = 0; t < 4; t++) {
                ushort4 pw;
                pw.x = f2b(s[4 * t + 0]); pw.y = f2b(s[4 * t + 1]);
                pw.z = f2b(s[4 * t + 2]); pw.w = f2b(s[4 * t + 3]);
                *(ushort4*)&Pl[w][c][16 * t + 4 * g] = pw;
            }
            const bf16x8 pA0 = *(const bf16x8*)&Pl[w][c][8 * g];       // kv 0..31
            const bf16x8 pA1 = *(const bf16x8*)&Pl[w][c][32 + 8 * g];  // kv 32..63

            float ar[4];
            #pragma unroll
            for (int r = 0; r < 4; r++) ar[r] = __shfl(alpha, 4 * g + r);

            // PV: o = P(16x64) * V(64x16chunk) + alpha*o
            __builtin_amdgcn_s_setprio(1);
            #pragma unroll
            for (int ch = 0; ch < 4; ch++) {
                f32x4 t = o[ch];
                #pragma unroll
                for (int r = 0; r < 4; r++) t[r] *= ar[r];
                t = __builtin_amdgcn_mfma_f32_16x16x32_bf16(pA0, vf[2 * ch], t, 0, 0, 0);
                o[ch] = __builtin_amdgcn_mfma_f32_16x16x32_bf16(pA1, vf[2 * ch + 1], t, 0, 0, 0);
            }
            __builtin_amdgcn_s_setprio(0);
        }

        // normalize + store ctx as bf16 [B,S,E]
        float linv[4];
        #pragma unroll
        for (int r = 0; r < 4; r++) linv[r] = 1.f / __shfl(lrun, 4 * g + r);
        #pragma unroll
        for (int ch = 0; ch < 4; ch++) {
            #pragma unroll
            for (int r = 0; r < 4; r++) {
                const int qg = qbase + w * 16 + 4 * g + r;
                const int e = hh * 64 + ch * 16 + c;
                Ctx[((size_t)(bb * Sc + qg)) * Ec + e] = f2b(o[ch][r] * linv[r]);
            }
        }
    }
}

// ---------------- Kernel C: output projection ----------------
__global__ __launch_bounds__(256) void out_proj(
    const unsigned short* __restrict__ Ctx, const float* __restrict__ Wo,
    const float* __restrict__ bo, float* __restrict__ Out)
{
    __shared__ unsigned short As[128][40];
    __shared__ unsigned short Bs[128][40];

    const int tid = threadIdx.x;
    const int m0 = blockIdx.y * 128, n0 = blockIdx.x * 128;
    const int lane = tid & 63, c = lane & 15, g = lane >> 4;
    const int w = tid >> 6;
    const int wr = (w >> 1) * 64, wc = (w & 1) * 64;

    f32x4 acc[4][4] = {};

    for (int k0 = 0; k0 < Ec; k0 += 32) {
        {   // A tile: bf16 direct
            const int r = tid >> 2, c8 = (tid & 3) * 8;
            #pragma unroll
            for (int p = 0; p < 2; p++) {
                ushort4 v0 = *(const ushort4*)&Ctx[(size_t)(m0 + r + 64 * p) * Ec + k0 + c8];
                ushort4 v1 = *(const ushort4*)&Ctx[(size_t)(m0 + r + 64 * p) * Ec + k0 + c8 + 4];
                *(ushort4*)&As[r + 64 * p][c8]     = v0;
                *(ushort4*)&As[r + 64 * p][c8 + 4] = v1;
            }
        }
        {   // B tile: Wo[k][n] -> Bs[n][k]
            const int kk = tid >> 5, cn = (tid & 31) * 4;
            #pragma unroll
            for (int p = 0; p < 4; p++) {
                float4 v = *(const float4*)&Wo[(size_t)(k0 + kk + 8 * p) * Ec + n0 + cn];
                Bs[cn + 0][kk + 8 * p] = f2b(v.x);
                Bs[cn + 1][kk + 8 * p] = f2b(v.y);
                Bs[cn + 2][kk + 8 * p] = f2b(v.z);
                Bs[cn + 3][kk + 8 * p] = f2b(v.w);
            }
        }
        __syncthreads();
        bf16x8 a[4], b[4];
        #pragma unroll
        for (int m = 0; m < 4; m++) a[m] = *(const bf16x8*)&As[wr + m * 16 + c][8 * g];
        #pragma unroll
        for (int n = 0; n < 4; n++) b[n] = *(const bf16x8*)&Bs[wc + n * 16 + c][8 * g];
        #pragma unroll
        for (int m = 0; m < 4; m++)
            #pragma unroll
            for (int n = 0; n < 4; n++)
                acc[m][n] = __builtin_amdgcn_mfma_f32_16x16x32_bf16(a[m], b[n], acc[m][n], 0, 0, 0);
        __syncthreads();
    }

    #pragma unroll
    for (int n = 0; n < 4; n++) {
        const int gn = n0 + wc + n * 16 + c;
        const float bv_ = bo[gn];
        #pragma unroll
        for (int m = 0; m < 4; m++) {
            #pragma unroll
            for (int r = 0; r < 4; r++) {
                const int gm = m0 + wr + m * 16 + 4 * g + r;
                Out[(size_t)gm * Ec + gn] = acc[m][n][r] + bv_;
            }
        }
    }
}

extern "C" void kernel_launch(void* const* d_in, const int* in_sizes, int n_in,
                              void* d_out, int out_size, void* d_ws, size_t ws_size,
                              hipStream_t stream) {
    const float* query = (const float*)d_in[0];
    const float* key   = (const float*)d_in[1];
    const float* value = (const float*)d_in[2];
    // d_in[3] = attn_mask (causal, implemented directly)
    const float* Wq = (const float*)d_in[4];
    const float* bq = (const float*)d_in[5];
    const float* Wk = (const float*)d_in[6];
    const float* bk = (const float*)d_in[7];
    const float* Wv = (const float*)d_in[8];
    const float* bv = (const float*)d_in[9];
    const float* Wo = (const float*)d_in[10];
    const float* bo = (const float*)d_in[11];

    const size_t n_elem = (size_t)Bc * Hc * Sc * DKc;  // 4194304
    unsigned short* Qw  = (unsigned short*)d_ws;
    unsigned short* Kw  = Qw + n_elem;
    unsigned short* Vt  = Kw + n_elem;
    unsigned short* Cx  = Vt + n_elem;

    qkv_proj<<<dim3(8, 32, 3), 256, 0, stream>>>(query, key, value, Wq, bq, Wk, bk, Wv, bv,
                                                 Qw, Kw, Vt);
    attn<<<dim3(512), 256, 0, stream>>>(Qw, Kw, Vt, Cx);
    out_proj<<<dim3(8, 32), 256, 0, stream>>>(Cx, Wo, bo, (float*)d_out);
}

// Round 3
// 209.526 us; speedup vs baseline: 2.0069x; 1.5007x over previous
//
#include <hip/hip_runtime.h>
#include <hip/hip_bf16.h>

typedef __attribute__((ext_vector_type(8))) short bf16x8;
typedef __attribute__((ext_vector_type(4))) float f32x4;

constexpr int Bc = 2, Sc = 2048, Ec = 1024, Hc = 16, DKc = 64;

__device__ __forceinline__ unsigned short f2b(float f) {
    union { float f; unsigned u; } v; v.f = f;
    unsigned u = v.u;
    return (unsigned short)((u + 0x7FFFu + ((u >> 16) & 1u)) >> 16);
}

// async global->LDS, 16B per lane; LDS base must be wave-uniform.
#define GLOAD16(ldsp, gp)                                                                  \
    __builtin_amdgcn_global_load_lds((const __attribute__((address_space(1))) void*)(gp),  \
                                     (__attribute__((address_space(3))) void*)(ldsp),      \
                                     16, 0, 0)

// ---------------- Prepass 1: X fp32 -> bf16 ----------------
__global__ __launch_bounds__(256) void conv_x(
    const float* __restrict__ Xq, const float* __restrict__ Xk, const float* __restrict__ Xv,
    unsigned short* __restrict__ Xb)
{
    const int z = blockIdx.y;
    const float* X = (z == 0) ? Xq : (z == 1) ? Xk : Xv;
    unsigned short* O = Xb + (size_t)z * 4194304;
    const int n4 = 4194304 / 4;
    for (int i = blockIdx.x * 256 + threadIdx.x; i < n4; i += gridDim.x * 256) {
        float4 v = ((const float4*)X)[i];
        ushort4 h; h.x = f2b(v.x); h.y = f2b(v.y); h.z = f2b(v.z); h.w = f2b(v.w);
        ((ushort4*)O)[i] = h;
    }
}

// ---------------- Prepass 2: W fp32 [k][n] -> bf16 Wt[z][n][k] ----------------
__global__ __launch_bounds__(256) void conv_w(
    const float* __restrict__ Wq, const float* __restrict__ Wk,
    const float* __restrict__ Wv, const float* __restrict__ Wo,
    unsigned short* __restrict__ Wt)
{
    const int z = blockIdx.z;
    const float* W = (z == 0) ? Wq : (z == 1) ? Wk : (z == 2) ? Wv : Wo;
    unsigned short* O = Wt + (size_t)z * 1048576;
    __shared__ unsigned short T[64][65];
    const int k0 = blockIdx.y * 64, n0 = blockIdx.x * 64;
    const int tx = threadIdx.x & 15, ty = threadIdx.x >> 4;
    #pragma unroll
    for (int p = 0; p < 4; p++) {
        float4 v = *(const float4*)&W[(size_t)(k0 + ty + 16 * p) * 1024 + n0 + 4 * tx];
        T[ty + 16 * p][4 * tx + 0] = f2b(v.x);
        T[ty + 16 * p][4 * tx + 1] = f2b(v.y);
        T[ty + 16 * p][4 * tx + 2] = f2b(v.z);
        T[ty + 16 * p][4 * tx + 3] = f2b(v.w);
    }
    __syncthreads();
    #pragma unroll
    for (int p = 0; p < 4; p++) {
        ushort4 o;
        o.x = T[4 * tx + 0][ty + 16 * p];
        o.y = T[4 * tx + 1][ty + 16 * p];
        o.z = T[4 * tx + 2][ty + 16 * p];
        o.w = T[4 * tx + 3][ty + 16 * p];
        *(ushort4*)&O[(size_t)(n0 + ty + 16 * p) * 1024 + k0 + 4 * tx] = o;
    }
}

// ---------------- GEMM main loop (m97 structure), shared via macro ----------------
// A [M][1024] bf16 row-major, Bm [N][1024] bf16 row-major (pre-transposed W).
// 128x128 tile, BK=32, 4 waves, global_load_lds staging, acc[4][4] per wave.
#define GEMM_CORE(Aptr, Bptr)                                                              \
    for (int k0 = 0; k0 < 1024; k0 += 32) {                                                \
        _Pragma("unroll")                                                                  \
        for (int i = 0; i < 2; i++) {                                                      \
            const int rb = 32 * w + 16 * i;                                                \
            GLOAD16(As + rb * 32, (Aptr) + (size_t)(m0 + rb + lr) * 1024 + k0 + lc);       \
            GLOAD16(Bs + rb * 32, (Bptr) + (size_t)(n0 + rb + lr) * 1024 + k0 + lc);       \
        }                                                                                  \
        __syncthreads();                                                                   \
        bf16x8 a[4], b[4];                                                                 \
        _Pragma("unroll")                                                                  \
        for (int m = 0; m < 4; m++) a[m] = *(const bf16x8*)(As + (wr + 16 * m + c) * 32 + 8 * g); \
        _Pragma("unroll")                                                                  \
        for (int n = 0; n < 4; n++) b[n] = *(const bf16x8*)(Bs + (wc + 16 * n + c) * 32 + 8 * g); \
        __builtin_amdgcn_s_setprio(1);                                                     \
        _Pragma("unroll")                                                                  \
        for (int m = 0; m < 4; m++)                                                        \
            _Pragma("unroll")                                                              \
            for (int n = 0; n < 4; n++)                                                    \
                acc[m][n] = __builtin_amdgcn_mfma_f32_16x16x32_bf16(a[m], b[n], acc[m][n], 0, 0, 0); \
        __builtin_amdgcn_s_setprio(0);                                                     \
        __syncthreads();                                                                   \
    }

// ---------------- Kernel A: QKV projection GEMM ----------------
__global__ __launch_bounds__(256) void gemm_qkv(
    const unsigned short* __restrict__ Xb, const unsigned short* __restrict__ Wt,
    const float* __restrict__ bq, const float* __restrict__ bk, const float* __restrict__ bv,
    unsigned short* __restrict__ Qw, unsigned short* __restrict__ Kw,
    unsigned short* __restrict__ Vt)
{
    const int z = blockIdx.z;
    const unsigned short* A  = Xb + (size_t)z * 4194304;
    const unsigned short* Bm = Wt + (size_t)z * 1048576;
    const float* bias = (z == 0) ? bq : (z == 1) ? bk : bv;

    __shared__ unsigned short As[128 * 32];
    __shared__ unsigned short Bs[128 * 32];

    const int tid = threadIdx.x;
    const int m0 = blockIdx.y * 128, n0 = blockIdx.x * 128;
    const int lane = tid & 63, c = lane & 15, g = lane >> 4;
    const int w = tid >> 6;
    const int wr = (w >> 1) * 64, wc = (w & 1) * 64;
    const int lr = lane >> 2, lc = (lane & 3) * 8;

    f32x4 acc[4][4] = {};
    GEMM_CORE(A, Bm)

    // epilogue: bias + scatter to head layout
    #pragma unroll
    for (int n = 0; n < 4; n++) {
        const int gn = n0 + wc + n * 16 + c;  // e index
        const float bv_ = bias[gn];
        const int h = gn >> 6, d = gn & 63;
        #pragma unroll
        for (int m = 0; m < 4; m++) {
            #pragma unroll
            for (int r = 0; r < 4; r++) {
                const int gm = m0 + wr + m * 16 + 4 * g + r;  // b*S+s
                const int bb = gm >> 11, s = gm & 2047;
                const float val = acc[m][n][r] + bv_;
                if (z == 0)
                    Qw[((size_t)(bb * Hc + h) * Sc + s) * DKc + d] = f2b(val * 0.125f);
                else if (z == 1)
                    Kw[((size_t)(bb * Hc + h) * Sc + s) * DKc + d] = f2b(val);
                else
                    Vt[((size_t)(bb * Hc + h) * DKc + d) * Sc + s] = f2b(val);
            }
        }
    }
}

// ---------------- Kernel C: output projection GEMM ----------------
__global__ __launch_bounds__(256) void gemm_out(
    const unsigned short* __restrict__ Ctx, const unsigned short* __restrict__ Wt,
    const float* __restrict__ bo, float* __restrict__ Out)
{
    const unsigned short* A  = Ctx;
    const unsigned short* Bm = Wt + (size_t)3 * 1048576;

    __shared__ unsigned short As[128 * 32];
    __shared__ unsigned short Bs[128 * 32];

    const int tid = threadIdx.x;
    const int m0 = blockIdx.y * 128, n0 = blockIdx.x * 128;
    const int lane = tid & 63, c = lane & 15, g = lane >> 4;
    const int w = tid >> 6;
    const int wr = (w >> 1) * 64, wc = (w & 1) * 64;
    const int lr = lane >> 2, lc = (lane & 3) * 8;

    f32x4 acc[4][4] = {};
    GEMM_CORE(A, Bm)

    #pragma unroll
    for (int n = 0; n < 4; n++) {
        const int gn = n0 + wc + n * 16 + c;
        const float bv_ = bo[gn];
        #pragma unroll
        for (int m = 0; m < 4; m++) {
            #pragma unroll
            for (int r = 0; r < 4; r++) {
                const int gm = m0 + wr + m * 16 + 4 * g + r;
                Out[(size_t)gm * Ec + gn] = acc[m][n][r] + bv_;
            }
        }
    }
}

// ---------------- Kernel B: causal flash attention (unchanged from r1) ----------------
__global__ __launch_bounds__(256) void attn(
    const unsigned short* __restrict__ Qw, const unsigned short* __restrict__ Kw,
    const unsigned short* __restrict__ Vt, unsigned short* __restrict__ Ctx)
{
    const int L = blockIdx.x;
    const int bh = L & 31, pair = L >> 5;
    const int tid = threadIdx.x, w = tid >> 6, lane = tid & 63;
    const int c = lane & 15, g = lane >> 4;
    const int bb = bh >> 4, hh = bh & 15;

    const unsigned short* Qh = Qw + (size_t)bh * Sc * DKc;
    const unsigned short* Kh = Kw + (size_t)bh * Sc * DKc;
    const unsigned short* Vh = Vt + (size_t)bh * DKc * Sc;

    __shared__ unsigned short Pl[4][16][68];

    for (int half = 0; half < 2; half++) {
        const int qt = half ? (31 - pair) : pair;
        const int qbase = qt * 64;
        const int qrow = qbase + w * 16 + c;

        const bf16x8 q0 = *(const bf16x8*)&Qh[(size_t)qrow * DKc + 8 * g];
        const bf16x8 q1 = *(const bf16x8*)&Qh[(size_t)qrow * DKc + 32 + 8 * g];

        float mrun = -1e30f, lrun = 0.f;
        f32x4 o[4] = {};

        const int ntiles = qt + 1;
        for (int j = 0; j < ntiles; j++) {
            const int kv0 = j * 64;
            const bool maskt = (j == qt);

            bf16x8 kf[8], vf[8];
            #pragma unroll
            for (int t = 0; t < 4; t++) {
                kf[2 * t]     = *(const bf16x8*)&Kh[(size_t)(kv0 + 16 * t + c) * DKc + 8 * g];
                kf[2 * t + 1] = *(const bf16x8*)&Kh[(size_t)(kv0 + 16 * t + c) * DKc + 32 + 8 * g];
            }
            #pragma unroll
            for (int ch = 0; ch < 4; ch++) {
                vf[2 * ch]     = *(const bf16x8*)&Vh[(size_t)(ch * 16 + c) * Sc + kv0 + 8 * g];
                vf[2 * ch + 1] = *(const bf16x8*)&Vh[(size_t)(ch * 16 + c) * Sc + kv0 + 32 + 8 * g];
            }

            f32x4 d[4] = {};
            __builtin_amdgcn_s_setprio(1);
            #pragma unroll
            for (int t = 0; t < 4; t++) {
                d[t] = __builtin_amdgcn_mfma_f32_16x16x32_bf16(kf[2 * t], q0, d[t], 0, 0, 0);
                d[t] = __builtin_amdgcn_mfma_f32_16x16x32_bf16(kf[2 * t + 1], q1, d[t], 0, 0, 0);
            }
            __builtin_amdgcn_s_setprio(0);

            float s[16];
            float tmax = -1e30f;
            if (maskt) {
                #pragma unroll
                for (int t = 0; t < 4; t++)
                    #pragma unroll
                    for (int r = 0; r < 4; r++) {
                        const int kv = kv0 + 16 * t + 4 * g + r;
                        const float v = (kv <= qrow) ? d[t][r] : -1e30f;
                        s[4 * t + r] = v;
                        tmax = fmaxf(tmax, v);
                    }
            } else {
                #pragma unroll
                for (int t = 0; t < 4; t++)
                    #pragma unroll
                    for (int r = 0; r < 4; r++) {
                        const float v = d[t][r];
                        s[4 * t + r] = v;
                        tmax = fmaxf(tmax, v);
                    }
            }
            tmax = fmaxf(tmax, __shfl_xor(tmax, 16));
            tmax = fmaxf(tmax, __shfl_xor(tmax, 32));
            const float mnew = fmaxf(mrun, tmax);
            const float alpha = __expf(mrun - mnew);
            float tsum = 0.f;
            #pragma unroll
            for (int i = 0; i < 16; i++) {
                s[i] = __expf(s[i] - mnew);
                tsum += s[i];
            }
            tsum += __shfl_xor(tsum, 16);
            tsum += __shfl_xor(tsum, 32);
            lrun = lrun * alpha + tsum;
            mrun = mnew;

            #pragma unroll
            for (int t = 0; t < 4; t++) {
                ushort4 pw;
                pw.x = f2b(s[4 * t + 0]); pw.y = f2b(s[4 * t + 1]);
                pw.z = f2b(s[4 * t + 2]); pw.w = f2b(s[4 * t + 3]);
                *(ushort4*)&Pl[w][c][16 * t + 4 * g] = pw;
            }
            const bf16x8 pA0 = *(const bf16x8*)&Pl[w][c][8 * g];
            const bf16x8 pA1 = *(const bf16x8*)&Pl[w][c][32 + 8 * g];

            float ar[4];
            #pragma unroll
            for (int r = 0; r < 4; r++) ar[r] = __shfl(alpha, 4 * g + r);

            __builtin_amdgcn_s_setprio(1);
            #pragma unroll
            for (int ch = 0; ch < 4; ch++) {
                f32x4 t = o[ch];
                #pragma unroll
                for (int r = 0; r < 4; r++) t[r] *= ar[r];
                t = __builtin_amdgcn_mfma_f32_16x16x32_bf16(pA0, vf[2 * ch], t, 0, 0, 0);
                o[ch] = __builtin_amdgcn_mfma_f32_16x16x32_bf16(pA1, vf[2 * ch + 1], t, 0, 0, 0);
            }
            __builtin_amdgcn_s_setprio(0);
        }

        float linv[4];
        #pragma unroll
        for (int r = 0; r < 4; r++) linv[r] = 1.f / __shfl(lrun, 4 * g + r);
        #pragma unroll
        for (int ch = 0; ch < 4; ch++) {
            #pragma unroll
            for (int r = 0; r < 4; r++) {
                const int qg = qbase + w * 16 + 4 * g + r;
                const int e = hh * 64 + ch * 16 + c;
                Ctx[((size_t)(bb * Sc + qg)) * Ec + e] = f2b(o[ch][r] * linv[r]);
            }
        }
    }
}

extern "C" void kernel_launch(void* const* d_in, const int* in_sizes, int n_in,
                              void* d_out, int out_size, void* d_ws, size_t ws_size,
                              hipStream_t stream) {
    const float* query = (const float*)d_in[0];
    const float* key   = (const float*)d_in[1];
    const float* value = (const float*)d_in[2];
    // d_in[3] = attn_mask (causal, implemented directly)
    const float* Wq = (const float*)d_in[4];
    const float* bq = (const float*)d_in[5];
    const float* Wk = (const float*)d_in[6];
    const float* bk = (const float*)d_in[7];
    const float* Wv = (const float*)d_in[8];
    const float* bv = (const float*)d_in[9];
    const float* Wo = (const float*)d_in[10];
    const float* bo = (const float*)d_in[11];

    const size_t n_elem = (size_t)Bc * Hc * Sc * DKc;  // 4194304
    unsigned short* Qw = (unsigned short*)d_ws;
    unsigned short* Kw = Qw + n_elem;
    unsigned short* Vt = Kw + n_elem;
    unsigned short* Cx = Vt + n_elem;
    unsigned short* Xb = Cx + n_elem;            // 3 * 4194304
    unsigned short* Wt = Xb + 3 * n_elem;        // 4 * 1048576

    conv_x<<<dim3(512, 3), 256, 0, stream>>>(query, key, value, Xb);
    conv_w<<<dim3(16, 16, 4), 256, 0, stream>>>(Wq, Wk, Wv, Wo, Wt);
    gemm_qkv<<<dim3(8, 32, 3), 256, 0, stream>>>(Xb, Wt, bq, bk, bv, Qw, Kw, Vt);
    attn<<<dim3(512), 256, 0, stream>>>(Qw, Kw, Vt, Cx);
    gemm_out<<<dim3(8, 32), 256, 0, stream>>>(Cx, Wt, bo, (float*)d_out);
}